// Round 3
// baseline (72.099 us; speedup 1.0000x reference)
//
#include <hip/hip_runtime.h>
#include <hip/hip_bf16.h>

// Grouped int32 GEMM, scaled, f32 out.
// A flat: per group [k, M] (k-major). B flat: per group [k, N].
// O[g][m][n] = (sum_k A[k][m]*B[k][n]) * scale[g][n] * pts[g][m]
// Values 0..127 -> exact in bf16; sums < 2^24 -> exact in f32 MFMA accum.
//
// Structure: 256 blocks (16 groups x 16 m-strips of 128 rows), 1 block/CU.
// A staged to LDS once (single barrier), A-fragments held in registers.
// Main loop over 16 n-chunks is BARRIER-FREE: each wave stages its own
// 32-row B slice into private LDS (reg-staged, double-buffered, prefetch
// by one chunk), so stores are never drained mid-kernel -> HBM-write paced.

#define M_ 2048
#define N_ 2048
#define G_ 16
#define KP 72     // LDS row stride in bf16 elems (144B, 16B-multiple)
#define KT 64     // max group k
#define NCH 16    // n-chunks of 128

typedef __attribute__((ext_vector_type(8))) short bf16x8;
typedef __attribute__((ext_vector_type(4))) float f32x4;
typedef __attribute__((ext_vector_type(4))) int   int4v;

// 8B-granule XOR swizzle within a row; same involution on write and read.
__device__ __forceinline__ int swz8(int row, int g) {
    return g ^ (((row >> 2) & 3) << 2);
}

// Cooperative stage of A strip [kg x 128m] -> dst[m][k] bf16, zero-padded to KT.
__device__ __forceinline__ void stage_tileA(const int* __restrict__ srcg,
                                            int col0, int kg,
                                            unsigned short (*dst)[KP], int tid)
{
    #pragma unroll
    for (int cc = 0; cc < 2; ++cc) {
        const int c  = tid + cc * 256;
        const int mc = c & 31;          // m-cell 0..31
        const int kc = c >> 5;          // k-granule 0..15
        const int k0 = kc * 4;
        const int mm = mc * 4;
        if (k0 >= kg) {
            uint2 z = {0u, 0u};
            #pragma unroll
            for (int j = 0; j < 4; ++j) {
                int r = mm + j;
                *(uint2*)((char*)&dst[r][0] + swz8(r, kc) * 8) = z;
            }
        } else {
            int4v L[4];
            const int off = k0 * M_ + col0 + mm;
            #pragma unroll
            for (int i = 0; i < 4; ++i)
                L[i] = (k0 + i < kg) ? *(const int4v*)(srcg + off + i * M_)
                                     : (int4v){0, 0, 0, 0};
            #pragma unroll
            for (int j = 0; j < 4; ++j) {
                unsigned u0 = __float_as_uint((float)L[0][j]);
                unsigned u1 = __float_as_uint((float)L[1][j]);
                unsigned u2 = __float_as_uint((float)L[2][j]);
                unsigned u3 = __float_as_uint((float)L[3][j]);
                uint2 w;
                w.x = (u0 >> 16) | (u1 & 0xFFFF0000u);
                w.y = (u2 >> 16) | (u3 & 0xFFFF0000u);
                int r = mm + j;
                *(uint2*)((char*)&dst[r][0] + swz8(r, kc) * 8) = w;
            }
        }
    }
}

__device__ __forceinline__ bf16x8 frag_read(const unsigned short (*s)[KP],
                                            int r, int gg)
{
    return *(const bf16x8*)((const char*)&s[r][0] + swz8(r, gg) * 8);
}

// Per-wave B slice loads: lane covers k = kb..kb+7 (consecutive), 4 n cols.
__device__ __forceinline__ void load_sliceB(int4v (&L)[8], const int* __restrict__ bg,
                                            int kg, int gncol, int kb)
{
    #pragma unroll
    for (int i = 0; i < 8; ++i) {
        int k = kb + i;
        L[i] = (k < kg) ? *(const int4v*)(bg + k * N_ + gncol)
                        : (int4v){0, 0, 0, 0};
    }
}

// Transpose-in-regs + bf16 pack -> 4 ds_write_b128 into wave-private buffer.
__device__ __forceinline__ void write_sliceB(const int4v (&L)[8],
                                             unsigned short (*buf)[KP],
                                             int n4, int gq)
{
    #pragma unroll
    for (int j = 0; j < 4; ++j) {
        uint4 w;
        w.x = (__float_as_uint((float)L[0][j]) >> 16) | (__float_as_uint((float)L[1][j]) & 0xFFFF0000u);
        w.y = (__float_as_uint((float)L[2][j]) >> 16) | (__float_as_uint((float)L[3][j]) & 0xFFFF0000u);
        w.z = (__float_as_uint((float)L[4][j]) >> 16) | (__float_as_uint((float)L[5][j]) & 0xFFFF0000u);
        w.w = (__float_as_uint((float)L[6][j]) >> 16) | (__float_as_uint((float)L[7][j]) & 0xFFFF0000u);
        int r = n4 + j;
        *(uint4*)((char*)&buf[r][0] + swz8(r, gq) * 8) = w;
    }
}

__device__ __forceinline__ void chunk_body(
    int nc, int do_prefetch, int kg, int nk,
    const int* __restrict__ bg,
    int4v (&Lc)[8], int4v (&Ln)[8],
    unsigned short (*bufW)[KP],
    const bf16x8 (&afr0)[8], const bf16x8 (&afr1)[8],
    const float* __restrict__ scg, const float (&pt_r)[8],
    float* __restrict__ outrow,
    int wn0, int n4, int kb, int gq, int l16, int lq)
{
    // write current chunk's B slice into private LDS buffer
    write_sliceB(Lc, bufW, n4, gq);
    // prefetch next chunk's loads (independent; overlaps with everything below)
    if (do_prefetch)
        load_sliceB(Ln, bg, kg, (nc + 1) * 128 + wn0 + n4, kb);

    // B fragments (wave-private rows -> only per-wave lgkm ordering needed)
    bf16x8 bfr0[2], bfr1[2];
    #pragma unroll
    for (int fn = 0; fn < 2; ++fn) {
        bfr0[fn] = frag_read(bufW, fn * 16 + l16, 0 + lq * 2);
        bfr1[fn] = frag_read(bufW, fn * 16 + l16, 8 + lq * 2);
    }

    const int ncol = nc * 128 + wn0;
    f32x4 sc[2];
    sc[0] = *(const f32x4*)&scg[ncol + 0  + lq * 4];
    sc[1] = *(const f32x4*)&scg[ncol + 16 + lq * 4];

    #pragma unroll
    for (int fm = 0; fm < 8; ++fm) {
        #pragma unroll
        for (int fn = 0; fn < 2; ++fn) {
            // swapped operands: D = B_frag x A_frag -> lane holds
            // m = l16 (col of D), n = lq*4 + r -> f32x4 store along n
            f32x4 d = __builtin_amdgcn_mfma_f32_16x16x32_bf16(
                bfr0[fn], afr0[fm], (f32x4){0.f, 0.f, 0.f, 0.f}, 0, 0, 0);
            if (nk == 2)
                d = __builtin_amdgcn_mfma_f32_16x16x32_bf16(
                    bfr1[fn], afr1[fm], d, 0, 0, 0);
            f32x4 v;
            #pragma unroll
            for (int r = 0; r < 4; ++r)
                v[r] = (d[r] * sc[fn][r]) * pt_r[fm];
            *(f32x4*)(outrow + (fm * 16 + l16) * N_ + ncol + fn * 16 + lq * 4) = v;
        }
    }
}

__global__ __launch_bounds__(256, 1)
void grouped_gemm_kernel(const int* __restrict__ a,
                         const int* __restrict__ b,
                         const float* __restrict__ scale,
                         const float* __restrict__ pts,
                         const int* __restrict__ gl,
                         float* __restrict__ out)
{
    __shared__ __align__(16) unsigned short As[128][KP];          // 18 KB
    __shared__ __align__(16) unsigned short Bs[4][2][32][KP];     // 36 KB

    const int tid   = threadIdx.x;
    const int bx    = blockIdx.x;
    const int ind   = bx >> 4;          // group
    const int strip = bx & 15;          // m-strip
    const int m0    = strip * 128;

    const int prefix = (ind == 0) ? 0 : gl[ind - 1];
    const int kg     = gl[ind] - prefix;

    float* outg = out + (size_t)ind * ((size_t)M_ * N_);

    if (kg <= 0) {
        // empty group: contiguous zero-fill of this 128-row strip (1 MB)
        float* o = outg + (size_t)m0 * N_;
        f32x4 z = {0.f, 0.f, 0.f, 0.f};
        #pragma unroll 4
        for (int i = tid; i < 128 * N_ / 4; i += 256)
            *(f32x4*)(o + i * 4) = z;
        return;
    }

    const int* ag = a + (size_t)prefix * M_;
    const int* bg = b + (size_t)prefix * N_;

    const int wid  = tid >> 6;
    const int lane = tid & 63;
    const int l16  = lane & 15;
    const int lq   = lane >> 4;

    // B staging lane map: 8 consecutive k per lane, 4 n cols
    const int kb  = (lane >> 3) * 8;
    const int n4  = (lane & 7) * 4;
    const int gq  = (lane >> 3) * 2;    // LDS write granule base
    const int wn0 = wid * 32;           // wave's n offset within a chunk

    // prologue: issue chunk-0 B loads early (hide under A stage + barrier)
    int4v LA[8], LB[8];
    load_sliceB(LA, bg, kg, 0 * 128 + wn0 + n4, kb);

    stage_tileA(ag, m0, kg, As, tid);
    __syncthreads();                    // the ONLY barrier in this kernel

    // A fragments to registers, held for the whole strip
    bf16x8 afr0[8], afr1[8];
    #pragma unroll
    for (int fm = 0; fm < 8; ++fm) {
        afr0[fm] = frag_read(As, fm * 16 + l16, 0 + lq * 2);
        afr1[fm] = frag_read(As, fm * 16 + l16, 8 + lq * 2);  // zeros if kg<=32
    }

    const int nk = (kg + 31) >> 5;      // 1 or 2 K=32 MFMA steps
    const float* scg = scale + (size_t)ind * N_;
    const float* ptg = pts   + (size_t)ind * M_;

    float pt_r[8];
    #pragma unroll
    for (int fm = 0; fm < 8; ++fm)
        pt_r[fm] = ptg[m0 + fm * 16 + l16];

    float* outrow = outg + (size_t)m0 * N_;

    unsigned short (*buf0)[KP] = Bs[wid][0];
    unsigned short (*buf1)[KP] = Bs[wid][1];

    #pragma unroll 1
    for (int t = 0; t < 8; ++t) {
        chunk_body(2 * t,     1,       kg, nk, bg, LA, LB, buf0,
                   afr0, afr1, scg, pt_r, outrow, wn0, n4, kb, gq, l16, lq);
        chunk_body(2 * t + 1, (t < 7), kg, nk, bg, LB, LA, buf1,
                   afr0, afr1, scg, pt_r, outrow, wn0, n4, kb, gq, l16, lq);
    }
}

extern "C" void kernel_launch(void* const* d_in, const int* in_sizes, int n_in,
                              void* d_out, int out_size, void* d_ws, size_t ws_size,
                              hipStream_t stream) {
    const int*   a     = (const int*)d_in[0];
    const int*   b     = (const int*)d_in[1];
    const float* scale = (const float*)d_in[2];
    const float* pts   = (const float*)d_in[3];
    const int*   gl    = (const int*)d_in[4];
    float*       out   = (float*)d_out;

    dim3 grid(G_ * 16);     // 256 blocks: one per CU
    dim3 block(256);
    grouped_gemm_kernel<<<grid, block, 0, stream>>>(a, b, scale, pts, gl, out);
}